// Round 3
// baseline (219.091 us; speedup 1.0000x reference)
//
#include <hip/hip_runtime.h>
#include <stdint.h>
#include <stddef.h>

#define AS1 __attribute__((address_space(1)))
#define AS3 __attribute__((address_space(3)))

typedef short bf16x8 __attribute__((ext_vector_type(8)));
typedef float f32x4 __attribute__((ext_vector_type(4)));
typedef unsigned short u16x8 __attribute__((ext_vector_type(8)));

static constexpr int N = 4096;
static constexpr int K = 2048;
static constexpr int BM = 128;         // legacy fallback tile
static constexpr int TILES = N / BM;   // 32
static constexpr int NBLK = TILES * TILES;  // 1024 (fallback)

// round-to-nearest-even f32 -> bf16
__device__ __forceinline__ unsigned short f2bf(float f) {
  union { float f; uint32_t u; } v; v.f = f;
  return (unsigned short)((v.u + 0x7FFFu + ((v.u >> 16) & 1u)) >> 16);
}

__global__ __launch_bounds__(256) void prep_kernel(
    const float* __restrict__ X, const float* __restrict__ Y,
    float* __restrict__ x2, float* __restrict__ y2,
    unsigned short* __restrict__ Xb, unsigned short* __restrict__ Yb, int wb) {
  const int row = blockIdx.x;
  const float* src = blockIdx.y ? Y : X;
  float* nrm = blockIdx.y ? y2 : x2;
  unsigned short* dst = blockIdx.y ? Yb : Xb;
  const size_t base = (size_t)row * K + threadIdx.x * 8;
  const float4 a = *(const float4*)(src + base);
  const float4 b = *(const float4*)(src + base + 4);
  double s = (double)a.x * a.x + (double)a.y * a.y + (double)a.z * a.z +
             (double)a.w * a.w + (double)b.x * b.x + (double)b.y * b.y +
             (double)b.z * b.z + (double)b.w * b.w;
  if (wb) {
    u16x8 o;
    o[0] = f2bf(a.x); o[1] = f2bf(a.y); o[2] = f2bf(a.z); o[3] = f2bf(a.w);
    o[4] = f2bf(b.x); o[5] = f2bf(b.y); o[6] = f2bf(b.z); o[7] = f2bf(b.w);
    *(u16x8*)(dst + base) = o;
  }
#pragma unroll
  for (int off = 32; off; off >>= 1) s += __shfl_down(s, off);
  __shared__ double red[4];
  if ((threadIdx.x & 63) == 0) red[threadIdx.x >> 6] = s;
  __syncthreads();
  if (threadIdx.x == 0) nrm[row] = (float)(red[0] + red[1] + red[2] + red[3]);
}

// ---------------- 256^2 8-phase kernel with 1-phase-ahead prefetch ----------
// LDS regions (shorts): RB(buf,O,ks) = buf*32768 + O*16384 + ks*8192 (16KB each).
// Storage within region: row r (0..255) x 4 chunks of 16B; logical chunk c
// stored at slot (c + (r>>2)) & 3 (rotation swizzle); source pre-swizzled.

#define RB(bb, o, ks) ((unsigned)((bb)*32768u + (o)*16384u + (ks)*8192u))

#define STAGE(O, KS, TT, BB)                                                   \
  do {                                                                         \
    const unsigned short* _sp = (O) ? Bpan : Apan;                             \
    const unsigned int _kof = (unsigned)(TT) * 64u + (KS) * 32u;               \
    const unsigned int _lb = RB(BB, O, KS) + wseg;                             \
    __builtin_amdgcn_global_load_lds(                                          \
        (const AS1 unsigned int*)(_sp + ((O) ? sB0 : sA0) + _kof),             \
        (AS3 unsigned int*)(lds + _lb), 16, 0, 0);                             \
    __builtin_amdgcn_global_load_lds(                                          \
        (const AS1 unsigned int*)(_sp + ((O) ? sB1 : sA1) + _kof),             \
        (AS3 unsigned int*)(lds + _lb + 512u), 16, 0, 0);                      \
  } while (0)

// One phase: prefetch next phase's fragments (6 ds_reads), barrier, counted
// lgkmcnt (covers PREVIOUS phase's reads only), stage 1 region, 16 MFMA,
// counted vmcnt, barrier.
#define PHASE(AU, BU, NH, LAs, LAh, LAb, LAk, LBs, LBb, LBk, LBf, SO, SK, ST, SBF) \
  do {                                                                         \
    _Pragma("unroll") for (int _q = 0; _q < 4; ++_q)                           \
        LAs[(LAh)*4 + _q] =                                                    \
            *(const bf16x8*)(lds + RB(LAb, 0, LAk) + aoff[(LAh)*4 + _q]);      \
    LBs[0] = *(const bf16x8*)(lds + RB(LBb, 1, LBk) + boff[(LBf)]);            \
    LBs[1] = *(const bf16x8*)(lds + RB(LBb, 1, LBk) + boff[(LBf) + 1]);        \
    __builtin_amdgcn_sched_barrier(0);                                         \
    __builtin_amdgcn_s_barrier();                                              \
    asm volatile("s_waitcnt lgkmcnt(6)" ::: "memory");                         \
    __builtin_amdgcn_sched_barrier(0);                                         \
    STAGE(SO, SK, ST, SBF);                                                    \
    __builtin_amdgcn_s_setprio(1);                                             \
    _Pragma("unroll") for (int _mi = 0; _mi < 8; ++_mi) {                      \
      acc[_mi][(NH)*2] = __builtin_amdgcn_mfma_f32_16x16x32_bf16(              \
          AU[_mi], BU[0], acc[_mi][(NH)*2], 0, 0, 0);                          \
      acc[_mi][(NH)*2 + 1] = __builtin_amdgcn_mfma_f32_16x16x32_bf16(          \
          AU[_mi], BU[1], acc[_mi][(NH)*2 + 1], 0, 0, 0);                      \
    }                                                                          \
    __builtin_amdgcn_s_setprio(0);                                             \
    asm volatile("s_waitcnt vmcnt(10)" ::: "memory");                          \
    __builtin_amdgcn_s_barrier();                                              \
  } while (0)

__global__ __launch_bounds__(512, 2) void mmd_gemm8(
    const unsigned short* __restrict__ Xb, const unsigned short* __restrict__ Yb,
    const float* __restrict__ x2, const float* __restrict__ y2,
    double* __restrict__ partials) {
  __shared__ __align__(16) unsigned short lds[65536];  // 128 KiB

  const int bid = blockIdx.x;
  const int logical = (bid & 7) * 96 + (bid >> 3);  // bijective XCD swizzle
  const int p = logical >> 8;                        // 0:XX 1:YY 2:XY
  const int t = logical & 255;
  const int i0 = (t & 15) << 8;
  const int j0 = (t >> 4) << 8;

  const unsigned short* Apan = (p == 1) ? Yb : Xb;
  const unsigned short* Bpan = (p == 0) ? Xb : Yb;
  const float* rn = (p == 1) ? y2 : x2;
  const float* cn = (p == 0) ? x2 : y2;
  const double wgt = (p == 2) ? -2.0 : 1.0;

  const int tid = threadIdx.x;
  const int w = tid >> 6, l = tid & 63;
  const int wm = w >> 2, wn = w & 3;
  const int lr = l & 15, lq = l >> 4;

  // staging per-thread constants
  const int ci0 = w * 128 + l;
  const int ci1 = ci0 + 64;
  const int r0 = ci0 >> 2, r1 = ci1 >> 2;
  const int c0 = ((ci0 & 3) - (r0 >> 2)) & 3;
  const int c1 = ((ci1 & 3) - (r1 >> 2)) & 3;
  const unsigned int sA0 = (unsigned)(i0 + r0) * (unsigned)K + (unsigned)(c0 * 8);
  const unsigned int sA1 = (unsigned)(i0 + r1) * (unsigned)K + (unsigned)(c1 * 8);
  const unsigned int sB0 = (unsigned)(j0 + r0) * (unsigned)K + (unsigned)(c0 * 8);
  const unsigned int sB1 = (unsigned)(j0 + r1) * (unsigned)K + (unsigned)(c1 * 8);
  const unsigned int wseg = (unsigned)w * 1024u;

  // fragment read offsets (shorts, within a region)
  unsigned int aoff[8], boff[4];
#pragma unroll
  for (int mi = 0; mi < 8; ++mi) {
    const int r = wm * 128 + mi * 16 + lr;
    aoff[mi] = (unsigned)(r * 32 + (((lq + (r >> 2)) & 3) * 8));
  }
#pragma unroll
  for (int ni = 0; ni < 4; ++ni) {
    const int rb = wn * 64 + ni * 16 + lr;
    boff[ni] = (unsigned)(rb * 32 + (((lq + (rb >> 2)) & 3) * 8));
  }

  f32x4 acc[8][4] = {};
  bf16x8 afX[8], afY[8], bX[2], bY[2];

  // Prologue: stage both buffers (16 loads/thread), publish first 8, prefetch
  // P1's fragments (A.k0(buf0) full + B.k0(buf0) frags 0,1 = 10 ds_reads).
  STAGE(0, 0, 0, 0); STAGE(1, 0, 0, 0); STAGE(0, 1, 0, 0); STAGE(1, 1, 0, 0);
  STAGE(0, 0, 1, 1); STAGE(1, 0, 1, 1); STAGE(0, 1, 1, 1); STAGE(1, 1, 1, 1);
  asm volatile("s_waitcnt vmcnt(8)" ::: "memory");
  __builtin_amdgcn_s_barrier();
#pragma unroll
  for (int q = 0; q < 8; ++q)
    afX[q] = *(const bf16x8*)(lds + RB(0, 0, 0) + aoff[q]);
  bX[0] = *(const bf16x8*)(lds + RB(0, 1, 0) + boff[0]);
  bX[1] = *(const bf16x8*)(lds + RB(0, 1, 0) + boff[1]);

#pragma unroll 1
  for (int tt = 0; tt < 32; tt += 2) {
    const int t2 = (tt + 2 < 32) ? tt + 2 : 31;
    const int t3 = (tt + 3 < 32) ? tt + 3 : 31;
    // buf0 (tile tt):  use-sets X/Y ping-pong; loads feed the NEXT phase.
    PHASE(afX, bX, 0, afY, 0, 0, 1, bY, 0, 0, 2, 0, 0, t2, 0);
    PHASE(afX, bY, 1, afY, 1, 0, 1, bX, 0, 1, 0, 1, 0, t2, 0);
    PHASE(afY, bX, 0, afX, 0, 1, 0, bY, 0, 1, 2, 0, 1, t2, 0);
    PHASE(afY, bY, 1, afX, 1, 1, 0, bX, 1, 0, 0, 1, 1, t2, 0);
    // buf1 (tile tt+1):
    PHASE(afX, bX, 0, afY, 0, 1, 1, bY, 1, 0, 2, 0, 0, t3, 1);
    PHASE(afX, bY, 1, afY, 1, 1, 1, bX, 1, 1, 0, 1, 0, t3, 1);
    PHASE(afY, bX, 0, afX, 0, 0, 0, bY, 1, 1, 2, 0, 1, t3, 1);
    PHASE(afY, bY, 1, afX, 1, 0, 0, bX, 0, 0, 0, 1, 1, t3, 1);
  }

  // Epilogue: expm1(-sqdist/D^2) Taylor; the "+1" cancels in 1/1/-2 weights.
  const float ce = -1.0f / (2048.0f * 2048.0f);
  double s = 0.0;
#pragma unroll
  for (int mi = 0; mi < 8; ++mi) {
#pragma unroll
    for (int r4 = 0; r4 < 4; ++r4) {
      const float rv = rn[i0 + wm * 128 + mi * 16 + lq * 4 + r4];
#pragma unroll
      for (int ni = 0; ni < 4; ++ni) {
        const float cv = cn[j0 + wn * 64 + ni * 16 + lr];
        const float tx = ce * (rv + cv - 2.0f * acc[mi][ni][r4]);
        const float v =
            tx * (1.0f + tx * (0.5f + tx * (0.16666667f + tx * 0.041666668f)));
        s += (double)v;
      }
    }
  }
#pragma unroll
  for (int off = 32; off; off >>= 1) s += __shfl_down(s, off);
  __shared__ double red[8];
  if (l == 0) red[w] = s;
  __syncthreads();
  if (tid == 0) {
    double tot = 0.0;
#pragma unroll
    for (int i = 0; i < 8; ++i) tot += red[i];
    partials[logical] = wgt * tot;
  }
}

// ---------------- legacy 128^2 kernel (ws-too-small fallback, f32 inputs) ----
__global__ __launch_bounds__(256) void mmd_gemm_f32(
    const float* __restrict__ Xp, const float* __restrict__ Yp,
    const float* __restrict__ x2, const float* __restrict__ y2,
    double* __restrict__ partials) {
  const int p = blockIdx.y;
  const float* Ap = (p == 1) ? Yp : Xp;
  const float* Bp = (p == 0) ? Xp : Yp;
  const float* rn = (p == 1) ? y2 : x2;
  const float* cn = (p == 0) ? x2 : y2;
  const double wgt = (p == 2) ? -2.0 : 1.0;

  const int bx = blockIdx.x;
  const int i0 = (bx & (TILES - 1)) * BM;
  const int j0 = (bx / TILES) * BM;

  __shared__ __align__(16) unsigned short As[BM * 64];
  __shared__ __align__(16) unsigned short Bs[BM * 64];

  const int tid = threadIdx.x;
  const int w = tid >> 6, l = tid & 63;
  const int m_base = (w >> 1) * 64, n_base = (w & 1) * 64;

  f32x4 acc[4][4] = {};

  for (int k0 = 0; k0 < K; k0 += 64) {
#pragma unroll
    for (int u = 0; u < 4; ++u) {
      const int f = u * 256 + tid;
      const int row = f >> 3;
      const int cir = f & 7;
      const int dstb = row * 128 + ((cir ^ (row & 7)) * 16);
      {
        const float* g = Ap + (size_t)(i0 + row) * K + k0 + cir * 8;
        const float4 v0 = *(const float4*)g;
        const float4 v1 = *(const float4*)(g + 4);
        u16x8 o;
        o[0] = f2bf(v0.x); o[1] = f2bf(v0.y); o[2] = f2bf(v0.z); o[3] = f2bf(v0.w);
        o[4] = f2bf(v1.x); o[5] = f2bf(v1.y); o[6] = f2bf(v1.z); o[7] = f2bf(v1.w);
        *(u16x8*)((char*)As + dstb) = o;
      }
      {
        const float* g = Bp + (size_t)(j0 + row) * K + k0 + cir * 8;
        const float4 v0 = *(const float4*)g;
        const float4 v1 = *(const float4*)(g + 4);
        u16x8 o;
        o[0] = f2bf(v0.x); o[1] = f2bf(v0.y); o[2] = f2bf(v0.z); o[3] = f2bf(v0.w);
        o[4] = f2bf(v1.x); o[5] = f2bf(v1.y); o[6] = f2bf(v1.z); o[7] = f2bf(v1.w);
        *(u16x8*)((char*)Bs + dstb) = o;
      }
    }
    __syncthreads();

#pragma unroll
    for (int kk = 0; kk < 64; kk += 32) {
      bf16x8 af2[4], bfr[4];
      const int lr = l & 15;
      const int ch = (kk >> 3) + (l >> 4);
#pragma unroll
      for (int mi = 0; mi < 4; ++mi) {
        const int r = m_base + mi * 16 + lr;
        af2[mi] = *(const bf16x8*)((const char*)As + r * 128 + ((ch ^ (r & 7)) * 16));
      }
#pragma unroll
      for (int ni = 0; ni < 4; ++ni) {
        const int r = n_base + ni * 16 + lr;
        bfr[ni] = *(const bf16x8*)((const char*)Bs + r * 128 + ((ch ^ (r & 7)) * 16));
      }
#pragma unroll
      for (int mi = 0; mi < 4; ++mi)
#pragma unroll
        for (int ni = 0; ni < 4; ++ni)
          acc[mi][ni] = __builtin_amdgcn_mfma_f32_16x16x32_bf16(
              af2[mi], bfr[ni], acc[mi][ni], 0, 0, 0);
    }
    __syncthreads();
  }

  const float ce = -1.0f / (2048.0f * 2048.0f);
  double s = 0.0;
  const int lr = l & 15, lq = l >> 4;
#pragma unroll
  for (int mi = 0; mi < 4; ++mi) {
#pragma unroll
    for (int r4 = 0; r4 < 4; ++r4) {
      const float rv = rn[i0 + m_base + mi * 16 + lq * 4 + r4];
#pragma unroll
      for (int ni = 0; ni < 4; ++ni) {
        const float cv = cn[j0 + n_base + ni * 16 + lr];
        const float tx = ce * (rv + cv - 2.0f * acc[mi][ni][r4]);
        const float v =
            tx * (1.0f + tx * (0.5f + tx * (0.16666667f + tx * 0.041666668f)));
        s += (double)v;
      }
    }
  }
#pragma unroll
  for (int off = 32; off; off >>= 1) s += __shfl_down(s, off);
  __shared__ double red[4];
  if (l == 0) red[w] = s;
  __syncthreads();
  if (tid == 0) partials[p * NBLK + bx] = wgt * (red[0] + red[1] + red[2] + red[3]);
}

__global__ __launch_bounds__(256) void finalize_kernel(
    const double* __restrict__ partials, float* __restrict__ out, int n) {
  double s = 0.0;
  for (int i = threadIdx.x; i < n; i += 256) s += partials[i];
#pragma unroll
  for (int off = 32; off; off >>= 1) s += __shfl_down(s, off);
  __shared__ double red[4];
  if ((threadIdx.x & 63) == 0) red[threadIdx.x >> 6] = s;
  __syncthreads();
  if (threadIdx.x == 0)
    out[0] = (float)((red[0] + red[1] + red[2] + red[3]) *
                     (1.0 / ((double)N * (double)N)));
}

extern "C" void kernel_launch(void* const* d_in, const int* in_sizes, int n_in,
                              void* d_out, int out_size, void* d_ws,
                              size_t ws_size, hipStream_t stream) {
  const float* X = (const float*)d_in[0];
  const float* Y = (const float*)d_in[1];
  char* ws = (char*)d_ws;

  double* partials = (double*)ws;
  float* x2 = (float*)(ws + 24576);
  float* y2 = (float*)(ws + 24576 + 16384);
  unsigned short* Xb = (unsigned short*)(ws + 65536);
  unsigned short* Yb = Xb + (size_t)N * K;
  const size_t need_fast = (size_t)65536 + (size_t)2 * N * K * 2;
  const bool fast = ws_size >= need_fast;

  prep_kernel<<<dim3(N, 2), 256, 0, stream>>>(X, Y, x2, y2, Xb, Yb, fast ? 1 : 0);
  if (fast) {
    mmd_gemm8<<<dim3(768), dim3(512), 0, stream>>>(Xb, Yb, x2, y2, partials);
    finalize_kernel<<<1, 256, 0, stream>>>(partials, (float*)d_out, 768);
  } else {
    mmd_gemm_f32<<<dim3(NBLK, 3), 256, 0, stream>>>(X, Y, x2, y2, partials);
    finalize_kernel<<<1, 256, 0, stream>>>(partials, (float*)d_out, 3072);
  }
}

// Round 5
// 198.152 us; speedup vs baseline: 1.1057x; 1.1057x over previous
//
#include <hip/hip_runtime.h>
#include <stdint.h>
#include <stddef.h>

#define AS1 __attribute__((address_space(1)))
#define AS3 __attribute__((address_space(3)))

typedef short bf16x8 __attribute__((ext_vector_type(8)));
typedef float f32x4 __attribute__((ext_vector_type(4)));
typedef unsigned short u16x8 __attribute__((ext_vector_type(8)));

static constexpr int N = 4096;
static constexpr int K = 2048;
static constexpr int BM = 128;         // legacy fallback tile
static constexpr int TILES = N / BM;   // 32
static constexpr int NBLK = TILES * TILES;  // 1024 (fallback)

// round-to-nearest-even f32 -> bf16
__device__ __forceinline__ unsigned short f2bf(float f) {
  union { float f; uint32_t u; } v; v.f = f;
  return (unsigned short)((v.u + 0x7FFFu + ((v.u >> 16) & 1u)) >> 16);
}

__global__ __launch_bounds__(256) void prep_kernel(
    const float* __restrict__ X, const float* __restrict__ Y,
    float* __restrict__ x2, float* __restrict__ y2,
    unsigned short* __restrict__ Xb, unsigned short* __restrict__ Yb, int wb) {
  const int row = blockIdx.x;
  const float* src = blockIdx.y ? Y : X;
  float* nrm = blockIdx.y ? y2 : x2;
  unsigned short* dst = blockIdx.y ? Yb : Xb;
  const size_t base = (size_t)row * K + threadIdx.x * 8;
  const float4 a = *(const float4*)(src + base);
  const float4 b = *(const float4*)(src + base + 4);
  double s = (double)a.x * a.x + (double)a.y * a.y + (double)a.z * a.z +
             (double)a.w * a.w + (double)b.x * b.x + (double)b.y * b.y +
             (double)b.z * b.z + (double)b.w * b.w;
  if (wb) {
    u16x8 o;
    o[0] = f2bf(a.x); o[1] = f2bf(a.y); o[2] = f2bf(a.z); o[3] = f2bf(a.w);
    o[4] = f2bf(b.x); o[5] = f2bf(b.y); o[6] = f2bf(b.z); o[7] = f2bf(b.w);
    *(u16x8*)(dst + base) = o;
  }
#pragma unroll
  for (int off = 32; off; off >>= 1) s += __shfl_down(s, off);
  __shared__ double red[4];
  if ((threadIdx.x & 63) == 0) red[threadIdx.x >> 6] = s;
  __syncthreads();
  if (threadIdx.x == 0) nrm[row] = (float)(red[0] + red[1] + red[2] + red[3]);
}

// ---------------- 256^2 8-phase kernel: XY term only (256 blocks) ----------
// Exact r2 schedule (validated). LDS regions (shorts):
// RB(buf,O,ks) = buf*32768 + O*16384 + ks*8192 (16KB each).
// Row r x 4 chunks of 16B; logical chunk c at slot (c + (r>>2)) & 3;
// source pre-swizzled so global_load_lds dest is linear.

#define RB(bb, o, ks) ((unsigned)((bb)*32768u + (o)*16384u + (ks)*8192u))
#define VM10 asm volatile("s_waitcnt vmcnt(10)" ::: "memory")
#define VM_NONE

#define STAGE(O, KS, TT, BB)                                                   \
  do {                                                                         \
    const unsigned short* _sp = (O) ? Bpan : Apan;                             \
    const unsigned int _kof = (unsigned)(TT) * 64u + (KS) * 32u;               \
    const unsigned int _lb = RB(BB, O, KS) + wseg;                             \
    __builtin_amdgcn_global_load_lds(                                          \
        (const AS1 unsigned int*)(_sp + ((O) ? sB0 : sA0) + _kof),             \
        (AS3 unsigned int*)(lds + _lb), 16, 0, 0);                             \
    __builtin_amdgcn_global_load_lds(                                          \
        (const AS1 unsigned int*)(_sp + ((O) ? sB1 : sA1) + _kof),             \
        (AS3 unsigned int*)(lds + _lb + 512u), 16, 0, 0);                      \
  } while (0)

#define PHASE(KS, NH, BB, VMW, ...)                                            \
  do {                                                                         \
    if constexpr ((NH) == 0) {                                                 \
      _Pragma("unroll") for (int _mi = 0; _mi < 8; ++_mi)                      \
          af[_mi] = *(const bf16x8*)(lds + RB(BB, 0, KS) + aoff[_mi]);         \
    }                                                                          \
    bf16x8 _b0 = *(const bf16x8*)(lds + RB(BB, 1, KS) + boff[(NH) * 2]);       \
    bf16x8 _b1 = *(const bf16x8*)(lds + RB(BB, 1, KS) + boff[(NH) * 2 + 1]);   \
    __VA_ARGS__;                                                               \
    __builtin_amdgcn_s_barrier();                                              \
    __builtin_amdgcn_s_setprio(1);                                             \
    _Pragma("unroll") for (int _mi = 0; _mi < 8; ++_mi) {                      \
      acc[_mi][(NH) * 2] = __builtin_amdgcn_mfma_f32_16x16x32_bf16(            \
          af[_mi], _b0, acc[_mi][(NH) * 2], 0, 0, 0);                          \
      acc[_mi][(NH) * 2 + 1] = __builtin_amdgcn_mfma_f32_16x16x32_bf16(        \
          af[_mi], _b1, acc[_mi][(NH) * 2 + 1], 0, 0, 0);                      \
    }                                                                          \
    __builtin_amdgcn_s_setprio(0);                                             \
    VMW;                                                                       \
    __builtin_amdgcn_s_barrier();                                              \
  } while (0)

#define TILE(T, BB)                                                            \
  do {                                                                         \
    const int _t1 = ((T) + 1 < 32) ? (T) + 1 : 31;                             \
    const int _t2 = ((T) + 2 < 32) ? (T) + 2 : 31;                             \
    PHASE(0, 0, BB, VM_NONE, STAGE(1, 1, _t1, 1 - (BB)));                      \
    PHASE(0, 1, BB, VM10, STAGE(0, 0, _t2, BB));                               \
    PHASE(1, 0, BB, VM_NONE, STAGE(1, 0, _t2, BB));                            \
    PHASE(1, 1, BB, VM10, STAGE(0, 1, _t2, BB));                               \
  } while (0)

__global__ __launch_bounds__(512, 2) void mmd_gemm8(
    const unsigned short* __restrict__ Xb, const unsigned short* __restrict__ Yb,
    const float* __restrict__ x2, const float* __restrict__ y2,
    double* __restrict__ partials) {
  __shared__ __align__(16) unsigned short lds[65536];  // 128 KiB

  const int bid = blockIdx.x;                       // 256 blocks (XY only)
  const int logical = (bid & 7) * 32 + (bid >> 3);  // bijective XCD swizzle
  const int i0 = (logical & 15) << 8;               // X row-tile
  const int j0 = (logical >> 4) << 8;               // Y row-tile

  const unsigned short* Apan = Xb;
  const unsigned short* Bpan = Yb;
  const float* rn = x2;
  const float* cn = y2;

  const int tid = threadIdx.x;
  const int w = tid >> 6, l = tid & 63;
  const int wm = w >> 2, wn = w & 3;
  const int lr = l & 15, lq = l >> 4;

  // staging per-thread constants
  const int ci0 = w * 128 + l;
  const int ci1 = ci0 + 64;
  const int r0 = ci0 >> 2, r1 = ci1 >> 2;
  const int c0 = ((ci0 & 3) - (r0 >> 2)) & 3;
  const int c1 = ((ci1 & 3) - (r1 >> 2)) & 3;
  const unsigned int sA0 = (unsigned)(i0 + r0) * (unsigned)K + (unsigned)(c0 * 8);
  const unsigned int sA1 = (unsigned)(i0 + r1) * (unsigned)K + (unsigned)(c1 * 8);
  const unsigned int sB0 = (unsigned)(j0 + r0) * (unsigned)K + (unsigned)(c0 * 8);
  const unsigned int sB1 = (unsigned)(j0 + r1) * (unsigned)K + (unsigned)(c1 * 8);
  const unsigned int wseg = (unsigned)w * 1024u;

  // fragment read offsets (shorts, within a region)
  unsigned int aoff[8], boff[4];
#pragma unroll
  for (int mi = 0; mi < 8; ++mi) {
    const int r = wm * 128 + mi * 16 + lr;
    aoff[mi] = (unsigned)(r * 32 + (((lq + (r >> 2)) & 3) * 8));
  }
#pragma unroll
  for (int ni = 0; ni < 4; ++ni) {
    const int rb = wn * 64 + ni * 16 + lr;
    boff[ni] = (unsigned)(rb * 32 + (((lq + (rb >> 2)) & 3) * 8));
  }

  f32x4 acc[8][4] = {};
  bf16x8 af[8];

  // Prologue: tile0 (buf0) fully + tile1 (buf1) A0,B0,A1 = 14 loads/thread.
  STAGE(0, 0, 0, 0); STAGE(1, 0, 0, 0); STAGE(0, 1, 0, 0); STAGE(1, 1, 0, 0);
  STAGE(0, 0, 1, 1); STAGE(1, 0, 1, 1); STAGE(0, 1, 1, 1);
  VM10;  // retire A0,B0 of buf0
  __builtin_amdgcn_s_barrier();

#pragma unroll 1
  for (int tt = 0; tt < 32; tt += 2) {
    TILE(tt, 0);
    TILE(tt + 1, 1);
  }

  // Epilogue: expm1(-sqdist/D^2) Taylor ("+1" cancels in 1/1/-2 weights).
  const float ce = -1.0f / (2048.0f * 2048.0f);
  double s = 0.0;
#pragma unroll
  for (int mi = 0; mi < 8; ++mi) {
#pragma unroll
    for (int r4 = 0; r4 < 4; ++r4) {
      const float rv = rn[i0 + wm * 128 + mi * 16 + lq * 4 + r4];
#pragma unroll
      for (int ni = 0; ni < 4; ++ni) {
        const float cv = cn[j0 + wn * 64 + ni * 16 + lr];
        const float tx = ce * (rv + cv - 2.0f * acc[mi][ni][r4]);
        const float v =
            tx * (1.0f + tx * (0.5f + tx * (0.16666667f + tx * 0.041666668f)));
        s += (double)v;
      }
    }
  }
#pragma unroll
  for (int off = 32; off; off >>= 1) s += __shfl_down(s, off);
  __shared__ double red[8];
  if (l == 0) red[w] = s;
  __syncthreads();
  if (tid == 0) {
    double tot = 0.0;
#pragma unroll
    for (int i = 0; i < 8; ++i) tot += red[i];
    partials[logical] = -2.0 * tot;
  }
}

// ------------- 128^2 kernel: symmetric XX/YY upper-tri (1056 blocks) -------
// r1-validated body (zero bank conflicts, 2 blocks/CU). Off-diagonal tiles
// weighted x2 (exact: same bf16 buffer => mirror tile is bit-identical).
__global__ __launch_bounds__(256) void mmd_sym128(
    const unsigned short* __restrict__ Xb, const unsigned short* __restrict__ Yb,
    const float* __restrict__ x2, const float* __restrict__ y2,
    double* __restrict__ partials) {
  const int bid = blockIdx.x;                        // 1056 blocks
  const int logical = (bid & 7) * 132 + (bid >> 3);  // bijective XCD swizzle
  const int p = (logical >= 528) ? 1 : 0;
  int jj = logical - (p ? 528 : 0);
  int rr = 0;
  while (jj >= 32 - rr) { jj -= 32 - rr; ++rr; }
  const int ti = rr, tj = rr + jj;
  const double wgt = (ti == tj) ? 1.0 : 2.0;

  const unsigned short* Pan = p ? Yb : Xb;
  const float* nrm = p ? y2 : x2;
  const int i0 = ti * 128, j0 = tj * 128;

  __shared__ __align__(16) unsigned short As[128 * 64];
  __shared__ __align__(16) unsigned short Bs[128 * 64];

  const int tid = threadIdx.x;
  const int w = tid >> 6, l = tid & 63;
  const int m_base = (w >> 1) * 64, n_base = (w & 1) * 64;
  const int lr = l & 15, lq = l >> 4;

  f32x4 acc[4][4] = {};

  for (int k0 = 0; k0 < K; k0 += 64) {
#pragma unroll
    for (int u = 0; u < 4; ++u) {
      const int seg = w * 4 + u;          // 16 segments x 64 chunks of 16B
      const int f = seg * 64 + l;
      const int row = f >> 3;
      const int scol = ((f & 7) ^ (row & 7)) * 8;  // inverse-swizzled source
      __builtin_amdgcn_global_load_lds(
          (const AS1 unsigned int*)(Pan + (size_t)(i0 + row) * K + k0 + scol),
          (AS3 unsigned int*)(As + seg * 512), 16, 0, 0);
      __builtin_amdgcn_global_load_lds(
          (const AS1 unsigned int*)(Pan + (size_t)(j0 + row) * K + k0 + scol),
          (AS3 unsigned int*)(Bs + seg * 512), 16, 0, 0);
    }
    __syncthreads();

#pragma unroll
    for (int kk = 0; kk < 64; kk += 32) {
      bf16x8 af2[4], bfr[4];
      const int ch = (kk >> 3) + lq;
#pragma unroll
      for (int mi = 0; mi < 4; ++mi) {
        const int r = m_base + mi * 16 + lr;
        af2[mi] = *(const bf16x8*)((const char*)As + r * 128 + ((ch ^ (r & 7)) * 16));
      }
#pragma unroll
      for (int ni = 0; ni < 4; ++ni) {
        const int r = n_base + ni * 16 + lr;
        bfr[ni] = *(const bf16x8*)((const char*)Bs + r * 128 + ((ch ^ (r & 7)) * 16));
      }
#pragma unroll
      for (int mi = 0; mi < 4; ++mi)
#pragma unroll
        for (int ni = 0; ni < 4; ++ni)
          acc[mi][ni] = __builtin_amdgcn_mfma_f32_16x16x32_bf16(
              af2[mi], bfr[ni], acc[mi][ni], 0, 0, 0);
    }
    __syncthreads();
  }

  const float ce = -1.0f / (2048.0f * 2048.0f);
  double s = 0.0;
#pragma unroll
  for (int mi = 0; mi < 4; ++mi) {
#pragma unroll
    for (int r4 = 0; r4 < 4; ++r4) {
      const float rv = nrm[i0 + m_base + mi * 16 + lq * 4 + r4];
#pragma unroll
      for (int ni = 0; ni < 4; ++ni) {
        const float cv = nrm[j0 + n_base + ni * 16 + lr];
        const float tx = ce * (rv + cv - 2.0f * acc[mi][ni][r4]);
        const float v =
            tx * (1.0f + tx * (0.5f + tx * (0.16666667f + tx * 0.041666668f)));
        s += (double)v;
      }
    }
  }
#pragma unroll
  for (int off = 32; off; off >>= 1) s += __shfl_down(s, off);
  __shared__ double red[4];
  if (l == 0) red[w] = s;
  __syncthreads();
  if (tid == 0)
    partials[256 + logical] = wgt * (red[0] + red[1] + red[2] + red[3]);
}

// ---------------- legacy 128^2 kernel (ws-too-small fallback, f32 inputs) ----
__global__ __launch_bounds__(256) void mmd_gemm_f32(
    const float* __restrict__ Xp, const float* __restrict__ Yp,
    const float* __restrict__ x2, const float* __restrict__ y2,
    double* __restrict__ partials) {
  const int p = blockIdx.y;
  const float* Ap = (p == 1) ? Yp : Xp;
  const float* Bp = (p == 0) ? Xp : Yp;
  const float* rn = (p == 1) ? y2 : x2;
  const float* cn = (p == 0) ? x2 : y2;
  const double wgt = (p == 2) ? -2.0 : 1.0;

  const int bx = blockIdx.x;
  const int i0 = (bx & (TILES - 1)) * BM;
  const int j0 = (bx / TILES) * BM;

  __shared__ __align__(16) unsigned short As[BM * 64];
  __shared__ __align__(16) unsigned short Bs[BM * 64];

  const int tid = threadIdx.x;
  const int w = tid >> 6, l = tid & 63;
  const int m_base = (w >> 1) * 64, n_base = (w & 1) * 64;

  f32x4 acc[4][4] = {};

  for (int k0 = 0; k0 < K; k0 += 64) {
#pragma unroll
    for (int u = 0; u < 4; ++u) {
      const int f = u * 256 + tid;
      const int row = f >> 3;
      const int cir = f & 7;
      const int dstb = row * 128 + ((cir ^ (row & 7)) * 16);
      {
        const float* g = Ap + (size_t)(i0 + row) * K + k0 + cir * 8;
        const float4 v0 = *(const float4*)g;
        const float4 v1 = *(const float4*)(g + 4);
        u16x8 o;
        o[0] = f2bf(v0.x); o[1] = f2bf(v0.y); o[2] = f2bf(v0.z); o[3] = f2bf(v0.w);
        o[4] = f2bf(v1.x); o[5] = f2bf(v1.y); o[6] = f2bf(v1.z); o[7] = f2bf(v1.w);
        *(u16x8*)((char*)As + dstb) = o;
      }
      {
        const float* g = Bp + (size_t)(j0 + row) * K + k0 + cir * 8;
        const float4 v0 = *(const float4*)g;
        const float4 v1 = *(const float4*)(g + 4);
        u16x8 o;
        o[0] = f2bf(v0.x); o[1] = f2bf(v0.y); o[2] = f2bf(v0.z); o[3] = f2bf(v0.w);
        o[4] = f2bf(v1.x); o[5] = f2bf(v1.y); o[6] = f2bf(v1.z); o[7] = f2bf(v1.w);
        *(u16x8*)((char*)Bs + dstb) = o;
      }
    }
    __syncthreads();

#pragma unroll
    for (int kk = 0; kk < 64; kk += 32) {
      bf16x8 af2[4], bfr[4];
      const int lr = l & 15;
      const int ch = (kk >> 3) + (l >> 4);
#pragma unroll
      for (int mi = 0; mi < 4; ++mi) {
        const int r = m_base + mi * 16 + lr;
        af2[mi] = *(const bf16x8*)((const char*)As + r * 128 + ((ch ^ (r & 7)) * 16));
      }
#pragma unroll
      for (int ni = 0; ni < 4; ++ni) {
        const int r = n_base + ni * 16 + lr;
        bfr[ni] = *(const bf16x8*)((const char*)Bs + r * 128 + ((ch ^ (r & 7)) * 16));
      }
#pragma unroll
      for (int mi = 0; mi < 4; ++mi)
#pragma unroll
        for (int ni = 0; ni < 4; ++ni)
          acc[mi][ni] = __builtin_amdgcn_mfma_f32_16x16x32_bf16(
              af2[mi], bfr[ni], acc[mi][ni], 0, 0, 0);
    }
    __syncthreads();
  }

  const float ce = -1.0f / (2048.0f * 2048.0f);
  double s = 0.0;
  const int lr = l & 15, lq = l >> 4;
#pragma unroll
  for (int mi = 0; mi < 4; ++mi) {
#pragma unroll
    for (int r4 = 0; r4 < 4; ++r4) {
      const float rv = rn[i0 + m_base + mi * 16 + lq * 4 + r4];
#pragma unroll
      for (int ni = 0; ni < 4; ++ni) {
        const float cv = cn[j0 + n_base + ni * 16 + lr];
        const float tx = ce * (rv + cv - 2.0f * acc[mi][ni][r4]);
        const float v =
            tx * (1.0f + tx * (0.5f + tx * (0.16666667f + tx * 0.041666668f)));
        s += (double)v;
      }
    }
  }
#pragma unroll
  for (int off = 32; off; off >>= 1) s += __shfl_down(s, off);
  __shared__ double red[4];
  if (l == 0) red[w] = s;
  __syncthreads();
  if (tid == 0) partials[p * NBLK + bx] = wgt * (red[0] + red[1] + red[2] + red[3]);
}

__global__ __launch_bounds__(256) void finalize_kernel(
    const double* __restrict__ partials, float* __restrict__ out, int n) {
  double s = 0.0;
  for (int i = threadIdx.x; i < n; i += 256) s += partials[i];
#pragma unroll
  for (int off = 32; off; off >>= 1) s += __shfl_down(s, off);
  __shared__ double red[4];
  if ((threadIdx.x & 63) == 0) red[threadIdx.x >> 6] = s;
  __syncthreads();
  if (threadIdx.x == 0)
    out[0] = (float)((red[0] + red[1] + red[2] + red[3]) *
                     (1.0 / ((double)N * (double)N)));
}

extern "C" void kernel_launch(void* const* d_in, const int* in_sizes, int n_in,
                              void* d_out, int out_size, void* d_ws,
                              size_t ws_size, hipStream_t stream) {
  const float* X = (const float*)d_in[0];
  const float* Y = (const float*)d_in[1];
  char* ws = (char*)d_ws;

  double* partials = (double*)ws;           // fast: 1312 f64; fallback: 3072
  float* x2 = (float*)(ws + 24576);
  float* y2 = (float*)(ws + 24576 + 16384);
  unsigned short* Xb = (unsigned short*)(ws + 65536);
  unsigned short* Yb = Xb + (size_t)N * K;
  const size_t need_fast = (size_t)65536 + (size_t)2 * N * K * 2;
  const bool fast = ws_size >= need_fast;

  prep_kernel<<<dim3(N, 2), 256, 0, stream>>>(X, Y, x2, y2, Xb, Yb, fast ? 1 : 0);
  if (fast) {
    mmd_gemm8<<<dim3(256), dim3(512), 0, stream>>>(Xb, Yb, x2, y2, partials);
    mmd_sym128<<<dim3(1056), dim3(256), 0, stream>>>(Xb, Yb, x2, y2, partials);
    finalize_kernel<<<1, 256, 0, stream>>>(partials, (float*)d_out, 1312);
  } else {
    mmd_gemm_f32<<<dim3(NBLK, 3), 256, 0, stream>>>(X, Y, x2, y2, partials);
    finalize_kernel<<<1, 256, 0, stream>>>(partials, (float*)d_out, 3072);
  }
}

// Round 6
// 182.951 us; speedup vs baseline: 1.1975x; 1.0831x over previous
//
#include <hip/hip_runtime.h>
#include <stdint.h>
#include <stddef.h>

#define AS1 __attribute__((address_space(1)))
#define AS3 __attribute__((address_space(3)))

typedef short bf16x8 __attribute__((ext_vector_type(8)));
typedef float f32x4 __attribute__((ext_vector_type(4)));
typedef unsigned short u16x8 __attribute__((ext_vector_type(8)));

static constexpr int N = 4096;
static constexpr int K = 2048;
static constexpr int BM = 128;         // legacy fallback tile
static constexpr int TILES = N / BM;   // 32
static constexpr int NBLK = TILES * TILES;  // 1024 (fallback)

// round-to-nearest-even f32 -> bf16
__device__ __forceinline__ unsigned short f2bf(float f) {
  union { float f; uint32_t u; } v; v.f = f;
  return (unsigned short)((v.u + 0x7FFFu + ((v.u >> 16) & 1u)) >> 16);
}

__global__ __launch_bounds__(256) void prep_kernel(
    const float* __restrict__ X, const float* __restrict__ Y,
    float* __restrict__ x2, float* __restrict__ y2,
    unsigned short* __restrict__ Xb, unsigned short* __restrict__ Yb, int wb) {
  const int row = blockIdx.x;
  const float* src = blockIdx.y ? Y : X;
  float* nrm = blockIdx.y ? y2 : x2;
  unsigned short* dst = blockIdx.y ? Yb : Xb;
  const size_t base = (size_t)row * K + threadIdx.x * 8;
  const float4 a = *(const float4*)(src + base);
  const float4 b = *(const float4*)(src + base + 4);
  double s = (double)a.x * a.x + (double)a.y * a.y + (double)a.z * a.z +
             (double)a.w * a.w + (double)b.x * b.x + (double)b.y * b.y +
             (double)b.z * b.z + (double)b.w * b.w;
  if (wb) {
    u16x8 o;
    o[0] = f2bf(a.x); o[1] = f2bf(a.y); o[2] = f2bf(a.z); o[3] = f2bf(a.w);
    o[4] = f2bf(b.x); o[5] = f2bf(b.y); o[6] = f2bf(b.z); o[7] = f2bf(b.w);
    *(u16x8*)(dst + base) = o;
  }
#pragma unroll
  for (int off = 32; off; off >>= 1) s += __shfl_down(s, off);
  __shared__ double red[4];
  if ((threadIdx.x & 63) == 0) red[threadIdx.x >> 6] = s;
  __syncthreads();
  if (threadIdx.x == 0) nrm[row] = (float)(red[0] + red[1] + red[2] + red[3]);
}

// ---------------- 256^2 8-phase kernel: 496-job list --------------------
// Jobs 0..255:   XY tile (ti=job&15 X-rows, tj=job>>4 Y-rows), w = -2
// Jobs 256..375: XX strict-upper off-diag tile (ti<tj), w = +2 (exact mirror)
// Jobs 376..495: YY strict-upper off-diag tile,          w = +2
// Exact r2/r5 schedule. LDS regions (shorts): RB(buf,O,ks) = buf*32768 +
// O*16384 + ks*8192. Row r x 4 chunks of 16B; logical chunk c at slot
// (c + (r>>2)) & 3; source pre-swizzled so global_load_lds dest is linear.

#define RB(bb, o, ks) ((unsigned)((bb)*32768u + (o)*16384u + (ks)*8192u))
#define VM10 asm volatile("s_waitcnt vmcnt(10)" ::: "memory")
#define VM_NONE

#define STAGE(O, KS, TT, BB)                                                   \
  do {                                                                         \
    const unsigned short* _sp = (O) ? Bpan : Apan;                             \
    const unsigned int _kof = (unsigned)(TT) * 64u + (KS) * 32u;               \
    const unsigned int _lb = RB(BB, O, KS) + wseg;                             \
    __builtin_amdgcn_global_load_lds(                                          \
        (const AS1 unsigned int*)(_sp + ((O) ? sB0 : sA0) + _kof),             \
        (AS3 unsigned int*)(lds + _lb), 16, 0, 0);                             \
    __builtin_amdgcn_global_load_lds(                                          \
        (const AS1 unsigned int*)(_sp + ((O) ? sB1 : sA1) + _kof),             \
        (AS3 unsigned int*)(lds + _lb + 512u), 16, 0, 0);                      \
  } while (0)

#define PHASE(KS, NH, BB, VMW, ...)                                            \
  do {                                                                         \
    if constexpr ((NH) == 0) {                                                 \
      _Pragma("unroll") for (int _mi = 0; _mi < 8; ++_mi)                      \
          af[_mi] = *(const bf16x8*)(lds + RB(BB, 0, KS) + aoff[_mi]);         \
    }                                                                          \
    bf16x8 _b0 = *(const bf16x8*)(lds + RB(BB, 1, KS) + boff[(NH) * 2]);       \
    bf16x8 _b1 = *(const bf16x8*)(lds + RB(BB, 1, KS) + boff[(NH) * 2 + 1]);   \
    __VA_ARGS__;                                                               \
    __builtin_amdgcn_s_barrier();                                              \
    __builtin_amdgcn_s_setprio(1);                                             \
    _Pragma("unroll") for (int _mi = 0; _mi < 8; ++_mi) {                      \
      acc[_mi][(NH) * 2] = __builtin_amdgcn_mfma_f32_16x16x32_bf16(            \
          af[_mi], _b0, acc[_mi][(NH) * 2], 0, 0, 0);                          \
      acc[_mi][(NH) * 2 + 1] = __builtin_amdgcn_mfma_f32_16x16x32_bf16(        \
          af[_mi], _b1, acc[_mi][(NH) * 2 + 1], 0, 0, 0);                      \
    }                                                                          \
    __builtin_amdgcn_s_setprio(0);                                             \
    VMW;                                                                       \
    __builtin_amdgcn_s_barrier();                                              \
  } while (0)

#define TILE(T, BB)                                                            \
  do {                                                                         \
    const int _t1 = ((T) + 1 < 32) ? (T) + 1 : 31;                             \
    const int _t2 = ((T) + 2 < 32) ? (T) + 2 : 31;                             \
    PHASE(0, 0, BB, VM_NONE, STAGE(1, 1, _t1, 1 - (BB)));                      \
    PHASE(0, 1, BB, VM10, STAGE(0, 0, _t2, BB));                               \
    PHASE(1, 0, BB, VM_NONE, STAGE(1, 0, _t2, BB));                            \
    PHASE(1, 1, BB, VM10, STAGE(0, 1, _t2, BB));                               \
  } while (0)

__global__ __launch_bounds__(512, 2) void mmd_gemm8(
    const unsigned short* __restrict__ Xb, const unsigned short* __restrict__ Yb,
    const float* __restrict__ x2, const float* __restrict__ y2,
    double* __restrict__ partials) {
  __shared__ __align__(16) unsigned short lds[65536];  // 128 KiB

  const int bid = blockIdx.x;                       // 496 blocks
  const int logical = (bid & 7) * 62 + (bid >> 3);  // bijective XCD swizzle
  int ti, tj;
  const unsigned short *Apan, *Bpan;
  const float *rn, *cn;
  double wgt;
  if (logical < 256) {            // XY
    ti = logical & 15; tj = logical >> 4;
    Apan = Xb; Bpan = Yb; rn = x2; cn = y2; wgt = -2.0;
  } else {                        // XX/YY strict-upper off-diagonal
    const int q = logical - 256;
    const int pp = q / 120;       // 0: XX, 1: YY
    int jj = q % 120;
    int rr = 0;
    while (jj >= 15 - rr) { jj -= 15 - rr; ++rr; }
    ti = rr; tj = rr + 1 + jj;    // ti < tj
    Apan = Bpan = pp ? Yb : Xb;
    rn = cn = pp ? y2 : x2;
    wgt = 2.0;
  }
  const int i0 = ti << 8, j0 = tj << 8;

  const int tid = threadIdx.x;
  const int w = tid >> 6, l = tid & 63;
  const int wm = w >> 2, wn = w & 3;
  const int lr = l & 15, lq = l >> 4;

  // staging per-thread constants
  const int ci0 = w * 128 + l;
  const int ci1 = ci0 + 64;
  const int r0 = ci0 >> 2, r1 = ci1 >> 2;
  const int c0 = ((ci0 & 3) - (r0 >> 2)) & 3;
  const int c1 = ((ci1 & 3) - (r1 >> 2)) & 3;
  const unsigned int sA0 = (unsigned)(i0 + r0) * (unsigned)K + (unsigned)(c0 * 8);
  const unsigned int sA1 = (unsigned)(i0 + r1) * (unsigned)K + (unsigned)(c1 * 8);
  const unsigned int sB0 = (unsigned)(j0 + r0) * (unsigned)K + (unsigned)(c0 * 8);
  const unsigned int sB1 = (unsigned)(j0 + r1) * (unsigned)K + (unsigned)(c1 * 8);
  const unsigned int wseg = (unsigned)w * 1024u;

  // fragment read offsets (shorts, within a region)
  unsigned int aoff[8], boff[4];
#pragma unroll
  for (int mi = 0; mi < 8; ++mi) {
    const int r = wm * 128 + mi * 16 + lr;
    aoff[mi] = (unsigned)(r * 32 + (((lq + (r >> 2)) & 3) * 8));
  }
#pragma unroll
  for (int ni = 0; ni < 4; ++ni) {
    const int rb = wn * 64 + ni * 16 + lr;
    boff[ni] = (unsigned)(rb * 32 + (((lq + (rb >> 2)) & 3) * 8));
  }

  f32x4 acc[8][4] = {};
  bf16x8 af[8];

  // Prologue: tile0 (buf0) fully + tile1 (buf1) A0,B0,A1 = 14 loads/thread.
  STAGE(0, 0, 0, 0); STAGE(1, 0, 0, 0); STAGE(0, 1, 0, 0); STAGE(1, 1, 0, 0);
  STAGE(0, 0, 1, 1); STAGE(1, 0, 1, 1); STAGE(0, 1, 1, 1);
  VM10;  // retire A0,B0 of buf0
  __builtin_amdgcn_s_barrier();

#pragma unroll 1
  for (int tt = 0; tt < 32; tt += 2) {
    TILE(tt, 0);
    TILE(tt + 1, 1);
  }

  // Epilogue: expm1(-sqdist/D^2) Taylor ("+1" cancels in 1/1/-2 weights).
  const float ce = -1.0f / (2048.0f * 2048.0f);
  double s = 0.0;
#pragma unroll
  for (int mi = 0; mi < 8; ++mi) {
#pragma unroll
    for (int r4 = 0; r4 < 4; ++r4) {
      const float rv = rn[i0 + wm * 128 + mi * 16 + lq * 4 + r4];
#pragma unroll
      for (int ni = 0; ni < 4; ++ni) {
        const float cv = cn[j0 + wn * 64 + ni * 16 + lr];
        const float tx = ce * (rv + cv - 2.0f * acc[mi][ni][r4]);
        const float v =
            tx * (1.0f + tx * (0.5f + tx * (0.16666667f + tx * 0.041666668f)));
        s += (double)v;
      }
    }
  }
#pragma unroll
  for (int off = 32; off; off >>= 1) s += __shfl_down(s, off);
  __shared__ double red[8];
  if (l == 0) red[w] = s;
  __syncthreads();
  if (tid == 0) {
    double tot = 0.0;
#pragma unroll
    for (int i = 0; i < 8; ++i) tot += red[i];
    partials[logical] = wgt * tot;
  }
}

// ------ 128^2 cleanup: diagonal 256-tiles via quadrant symmetry (96 blocks) -
// Job: pair p x diag-tile d (0..15) x sub {d00 w1, d01 w2, d11 w1}.
__global__ __launch_bounds__(256) void mmd_sym128(
    const unsigned short* __restrict__ Xb, const unsigned short* __restrict__ Yb,
    const float* __restrict__ x2, const float* __restrict__ y2,
    double* __restrict__ partials) {
  const int bid = blockIdx.x;                       // 96 blocks
  const int logical = (bid & 7) * 12 + (bid >> 3);  // bijective XCD swizzle
  const int p = logical / 48;
  const int r2_ = logical % 48;
  const int d = r2_ / 3;
  const int sub = r2_ % 3;
  const double wgt = (sub == 1) ? 2.0 : 1.0;

  const unsigned short* Pan = p ? Yb : Xb;
  const float* nrm = p ? y2 : x2;
  const int i0 = d * 256 + ((sub == 2) ? 128 : 0);
  const int j0 = d * 256 + ((sub >= 1) ? 128 : 0);

  __shared__ __align__(16) unsigned short As[128 * 64];
  __shared__ __align__(16) unsigned short Bs[128 * 64];

  const int tid = threadIdx.x;
  const int w = tid >> 6, l = tid & 63;
  const int m_base = (w >> 1) * 64, n_base = (w & 1) * 64;
  const int lr = l & 15, lq = l >> 4;

  f32x4 acc[4][4] = {};

  for (int k0 = 0; k0 < K; k0 += 64) {
#pragma unroll
    for (int u = 0; u < 4; ++u) {
      const int seg = w * 4 + u;          // 16 segments x 64 chunks of 16B
      const int f = seg * 64 + l;
      const int row = f >> 3;
      const int scol = ((f & 7) ^ (row & 7)) * 8;  // inverse-swizzled source
      __builtin_amdgcn_global_load_lds(
          (const AS1 unsigned int*)(Pan + (size_t)(i0 + row) * K + k0 + scol),
          (AS3 unsigned int*)(As + seg * 512), 16, 0, 0);
      __builtin_amdgcn_global_load_lds(
          (const AS1 unsigned int*)(Pan + (size_t)(j0 + row) * K + k0 + scol),
          (AS3 unsigned int*)(Bs + seg * 512), 16, 0, 0);
    }
    __syncthreads();

#pragma unroll
    for (int kk = 0; kk < 64; kk += 32) {
      bf16x8 af2[4], bfr[4];
      const int ch = (kk >> 3) + lq;
#pragma unroll
      for (int mi = 0; mi < 4; ++mi) {
        const int r = m_base + mi * 16 + lr;
        af2[mi] = *(const bf16x8*)((const char*)As + r * 128 + ((ch ^ (r & 7)) * 16));
      }
#pragma unroll
      for (int ni = 0; ni < 4; ++ni) {
        const int r = n_base + ni * 16 + lr;
        bfr[ni] = *(const bf16x8*)((const char*)Bs + r * 128 + ((ch ^ (r & 7)) * 16));
      }
#pragma unroll
      for (int mi = 0; mi < 4; ++mi)
#pragma unroll
        for (int ni = 0; ni < 4; ++ni)
          acc[mi][ni] = __builtin_amdgcn_mfma_f32_16x16x32_bf16(
              af2[mi], bfr[ni], acc[mi][ni], 0, 0, 0);
    }
    __syncthreads();
  }

  const float ce = -1.0f / (2048.0f * 2048.0f);
  double s = 0.0;
#pragma unroll
  for (int mi = 0; mi < 4; ++mi) {
#pragma unroll
    for (int r4 = 0; r4 < 4; ++r4) {
      const float rv = nrm[i0 + m_base + mi * 16 + lq * 4 + r4];
#pragma unroll
      for (int ni = 0; ni < 4; ++ni) {
        const float cv = nrm[j0 + n_base + ni * 16 + lr];
        const float tx = ce * (rv + cv - 2.0f * acc[mi][ni][r4]);
        const float v =
            tx * (1.0f + tx * (0.5f + tx * (0.16666667f + tx * 0.041666668f)));
        s += (double)v;
      }
    }
  }
#pragma unroll
  for (int off = 32; off; off >>= 1) s += __shfl_down(s, off);
  __shared__ double red[4];
  if (l == 0) red[w] = s;
  __syncthreads();
  if (tid == 0)
    partials[496 + logical] = wgt * (red[0] + red[1] + red[2] + red[3]);
}

// ---------------- legacy 128^2 kernel (ws-too-small fallback, f32 inputs) ----
__global__ __launch_bounds__(256) void mmd_gemm_f32(
    const float* __restrict__ Xp, const float* __restrict__ Yp,
    const float* __restrict__ x2, const float* __restrict__ y2,
    double* __restrict__ partials) {
  const int p = blockIdx.y;
  const float* Ap = (p == 1) ? Yp : Xp;
  const float* Bp = (p == 0) ? Xp : Yp;
  const float* rn = (p == 1) ? y2 : x2;
  const float* cn = (p == 0) ? x2 : y2;
  const double wgt = (p == 2) ? -2.0 : 1.0;

  const int bx = blockIdx.x;
  const int i0 = (bx & (TILES - 1)) * BM;
  const int j0 = (bx / TILES) * BM;

  __shared__ __align__(16) unsigned short As[BM * 64];
  __shared__ __align__(16) unsigned short Bs[BM * 64];

  const int tid = threadIdx.x;
  const int w = tid >> 6, l = tid & 63;
  const int m_base = (w >> 1) * 64, n_base = (w & 1) * 64;

  f32x4 acc[4][4] = {};

  for (int k0 = 0; k0 < K; k0 += 64) {
#pragma unroll
    for (int u = 0; u < 4; ++u) {
      const int f = u * 256 + tid;
      const int row = f >> 3;
      const int cir = f & 7;
      const int dstb = row * 128 + ((cir ^ (row & 7)) * 16);
      {
        const float* g = Ap + (size_t)(i0 + row) * K + k0 + cir * 8;
        const float4 v0 = *(const float4*)g;
        const float4 v1 = *(const float4*)(g + 4);
        u16x8 o;
        o[0] = f2bf(v0.x); o[1] = f2bf(v0.y); o[2] = f2bf(v0.z); o[3] = f2bf(v0.w);
        o[4] = f2bf(v1.x); o[5] = f2bf(v1.y); o[6] = f2bf(v1.z); o[7] = f2bf(v1.w);
        *(u16x8*)((char*)As + dstb) = o;
      }
      {
        const float* g = Bp + (size_t)(j0 + row) * K + k0 + cir * 8;
        const float4 v0 = *(const float4*)g;
        const float4 v1 = *(const float4*)(g + 4);
        u16x8 o;
        o[0] = f2bf(v0.x); o[1] = f2bf(v0.y); o[2] = f2bf(v0.z); o[3] = f2bf(v0.w);
        o[4] = f2bf(v1.x); o[5] = f2bf(v1.y); o[6] = f2bf(v1.z); o[7] = f2bf(v1.w);
        *(u16x8*)((char*)Bs + dstb) = o;
      }
    }
    __syncthreads();

#pragma unroll
    for (int kk = 0; kk < 64; kk += 32) {
      bf16x8 af2[4], bfr[4];
      const int lr = l & 15;
      const int ch = (kk >> 3) + (l >> 4);
#pragma unroll
      for (int mi = 0; mi < 4; ++mi) {
        const int r = m_base + mi * 16 + lr;
        af2[mi] = *(const bf16x8*)((const char*)As + r * 128 + ((ch ^ (r & 7)) * 16));
      }
#pragma unroll
      for (int ni = 0; ni < 4; ++ni) {
        const int r = n_base + ni * 16 + lr;
        bfr[ni] = *(const bf16x8*)((const char*)Bs + r * 128 + ((ch ^ (r & 7)) * 16));
      }
#pragma unroll
      for (int mi = 0; mi < 4; ++mi)
#pragma unroll
        for (int ni = 0; ni < 4; ++ni)
          acc[mi][ni] = __builtin_amdgcn_mfma_f32_16x16x32_bf16(
              af2[mi], bfr[ni], acc[mi][ni], 0, 0, 0);
    }
    __syncthreads();
  }

  const float ce = -1.0f / (2048.0f * 2048.0f);
  double s = 0.0;
  const int lr = l & 15, lq = l >> 4;
#pragma unroll
  for (int mi = 0; mi < 4; ++mi) {
#pragma unroll
    for (int r4 = 0; r4 < 4; ++r4) {
      const float rv = rn[i0 + m_base + mi * 16 + lq * 4 + r4];
#pragma unroll
      for (int ni = 0; ni < 4; ++ni) {
        const float cv = cn[j0 + n_base + ni * 16 + lr];
        const float tx = ce * (rv + cv - 2.0f * acc[mi][ni][r4]);
        const float v =
            tx * (1.0f + tx * (0.5f + tx * (0.16666667f + tx * 0.041666668f)));
        s += (double)v;
      }
    }
  }
#pragma unroll
  for (int off = 32; off; off >>= 1) s += __shfl_down(s, off);
  __shared__ double red[4];
  if (l == 0) red[w] = s;
  __syncthreads();
  if (tid == 0) partials[p * NBLK + bx] = wgt * (red[0] + red[1] + red[2] + red[3]);
}

__global__ __launch_bounds__(256) void finalize_kernel(
    const double* __restrict__ partials, float* __restrict__ out, int n) {
  double s = 0.0;
  for (int i = threadIdx.x; i < n; i += 256) s += partials[i];
#pragma unroll
  for (int off = 32; off; off >>= 1) s += __shfl_down(s, off);
  __shared__ double red[4];
  if ((threadIdx.x & 63) == 0) red[threadIdx.x >> 6] = s;
  __syncthreads();
  if (threadIdx.x == 0)
    out[0] = (float)((red[0] + red[1] + red[2] + red[3]) *
                     (1.0 / ((double)N * (double)N)));
}

extern "C" void kernel_launch(void* const* d_in, const int* in_sizes, int n_in,
                              void* d_out, int out_size, void* d_ws,
                              size_t ws_size, hipStream_t stream) {
  const float* X = (const float*)d_in[0];
  const float* Y = (const float*)d_in[1];
  char* ws = (char*)d_ws;

  double* partials = (double*)ws;           // fast: 592 f64; fallback: 3072
  float* x2 = (float*)(ws + 24576);
  float* y2 = (float*)(ws + 24576 + 16384);
  unsigned short* Xb = (unsigned short*)(ws + 65536);
  unsigned short* Yb = Xb + (size_t)N * K;
  const size_t need_fast = (size_t)65536 + (size_t)2 * N * K * 2;
  const bool fast = ws_size >= need_fast;

  prep_kernel<<<dim3(N, 2), 256, 0, stream>>>(X, Y, x2, y2, Xb, Yb, fast ? 1 : 0);
  if (fast) {
    mmd_gemm8<<<dim3(496), dim3(512), 0, stream>>>(Xb, Yb, x2, y2, partials);
    mmd_sym128<<<dim3(96), dim3(256), 0, stream>>>(Xb, Yb, x2, y2, partials);
    finalize_kernel<<<1, 256, 0, stream>>>(partials, (float*)d_out, 592);
  } else {
    mmd_gemm_f32<<<dim3(NBLK, 3), 256, 0, stream>>>(X, Y, x2, y2, partials);
    finalize_kernel<<<1, 256, 0, stream>>>(partials, (float*)d_out, 3072);
  }
}